// Round 3
// baseline (433.591 us; speedup 1.0000x reference)
//
#include <hip/hip_runtime.h>

// GlobalShiftV2Portion: x shape (B=8, C=512, H=128, W=128) fp32.
// Channels [0,256): identity. Channels [256,512): per-channel permutation of
// the four 64x64 quadrants: q = (c-256)>>6, t_dst = (h>>6)*2 + (w>>6),
// t_src = (q + t_dst) & 3, (h%64, w%64) preserved.
//
// Pure memory-bound: 256 MiB read + 256 MiB write. float4 per thread,
// fully coalesced on both sides (quadrant offsets are 256B-aligned).

#define B 8
#define C 512
#define H 128
#define W 128
#define W4 (W / 4)              // 32 float4 per row
#define TOTAL4 (B * C * H * W4) // 16,777,216

__global__ __launch_bounds__(256) void shift_quadrants_kernel(
    const float4* __restrict__ in, float4* __restrict__ out) {
  int stride = gridDim.x * blockDim.x;
  for (int i = blockIdx.x * blockDim.x + threadIdx.x; i < TOTAL4; i += stride) {
    // i = (((b*512 + c)*128 + h)*32 + w4)
    int w4 = i & (W4 - 1);        // w/4 in [0,32)
    int h  = (i >> 5) & (H - 1);  // [0,128)
    int c  = (i >> 12) & (C - 1); // [0,512)
    int src = i;
    if (c >= 256) {
      int q      = (c - 256) >> 6;                 // [0,4)
      int t_dst  = ((h >> 6) << 1) | (w4 >> 4);    // dest quadrant
      int t_src  = (q + t_dst) & 3;                // source quadrant
      int h_src  = ((t_src >> 1) << 6) | (h & 63);
      int w4_src = ((t_src & 1) << 4) | (w4 & 15);
      src = (i & ~0xFFF) | (h_src << 5) | w4_src;  // replace low 12 bits (h,w4)
    }
    out[i] = in[src];
  }
}

extern "C" void kernel_launch(void* const* d_in, const int* in_sizes, int n_in,
                              void* d_out, int out_size, void* d_ws, size_t ws_size,
                              hipStream_t stream) {
  const float4* in = (const float4*)d_in[0];
  float4* out = (float4*)d_out;
  // 2048 blocks x 256 threads, grid-stride (32 iters/thread) — saturates HBM
  // with ~8 waves/SIMD worth of independent in-flight loads.
  shift_quadrants_kernel<<<2048, 256, 0, stream>>>(in, out);
}

// Round 8
// 419.128 us; speedup vs baseline: 1.0345x; 1.0345x over previous
//
#include <hip/hip_runtime.h>

// GlobalShiftV2Portion: x shape (B=8, C=512, H=128, W=128) fp32.
// Channels [0,256): identity. Channels [256,512): per-channel permutation of
// the four 64x64 quadrants: q = (c>>6)&3, t_dst = (h>>6)*2 + (w>>6),
// t_src = (q + t_dst) & 3, (h%64, w%64) preserved.
//
// Pure memory-bound: 256 MiB read + 256 MiB write, both sides 16B-coalesced.
// R3 verified correct (absmax 0.0); kernel < 163 us (absent from rocprof top-5;
// harness poison fills run at 6.4-6.5 TB/s = observed write ceiling).
// R4 fix: nontemporal builtins need a NATIVE clang vector type, not
// HIP_vector_type<float,4> -> use ext_vector_type(4) float.

typedef float f32x4 __attribute__((ext_vector_type(4)));

#define TOTAL4 16777216          // 8*512*128*32 float4s
#define NBLK   2048
#define NTHR   256
#define STRIDE (NBLK * NTHR)     // 524288
#define ITERS  (TOTAL4 / STRIDE) // 32 — compile-time trip count

__global__ __launch_bounds__(NTHR) void shift_quadrants_kernel(
    const f32x4* __restrict__ in, f32x4* __restrict__ out) {
  int base = blockIdx.x * NTHR + threadIdx.x;
#pragma unroll 4
  for (int it = 0; it < ITERS; ++it) {
    int i = base + it * STRIDE;
    // i = (((b*512 + c)*128 + h)*32 + w4)
    int w4 = i & 31;          // w/4 in [0,32)
    int h  = (i >> 5) & 127;  // [0,128)
    int c  = (i >> 12) & 511; // [0,512)
    int src = i;
    if (c >= 256) {
      int q      = (c >> 6) & 3;                   // == (c-256)>>6 for c>=256
      int t_dst  = ((h >> 6) << 1) | (w4 >> 4);    // dest quadrant
      int t_src  = (q + t_dst) & 3;                // source quadrant
      int h_src  = ((t_src >> 1) << 6) | (h & 63);
      int w4_src = ((t_src & 1) << 4) | (w4 & 15);
      src = (i & ~0xFFF) | (h_src << 5) | w4_src;  // replace low 12 bits (h,w4)
    }
    f32x4 v = __builtin_nontemporal_load(&in[src]);
    __builtin_nontemporal_store(v, &out[i]);
  }
}

extern "C" void kernel_launch(void* const* d_in, const int* in_sizes, int n_in,
                              void* d_out, int out_size, void* d_ws, size_t ws_size,
                              hipStream_t stream) {
  const f32x4* in = (const f32x4*)d_in[0];
  f32x4* out = (f32x4*)d_out;
  shift_quadrants_kernel<<<NBLK, NTHR, 0, stream>>>(in, out);
}